// Round 3
// baseline (337.488 us; speedup 1.0000x reference)
//
#include <hip/hip_runtime.h>
#include <hip/hip_bf16.h>

typedef __attribute__((ext_vector_type(8))) short short8;   // 8 bf16 (A/B frag)
typedef __attribute__((ext_vector_type(4))) short bf16x4;   // 4 bf16 (8B store)
typedef __attribute__((ext_vector_type(4))) float f32x4;    // 4 fp32 (C/D frag)

// b=32, C=128, n=4096, heads=4, dh=32. All I/O fp32; MFMA bf16, fp32 accum.
// K1: grid 1024 = 32 b * 32 groups, 2 tiles of 64 px each; LDS 33 KB -> 4 blocks/CU
// single-phase residency (16 waves/CU). kbuf/vbuf are [128][32] half-width; per tile:
// q section, then 2x { k-half -> v-half -> phase4-half } (same-wave RAW, no barrier).
//
// ws (float units), offsets unchanged:
//   Sp  bf16 frag-major [32][32][4][4x256] @ 0        (exactly fills 2097152 fl)
//   Zp  bf16 [32][32][128]  @ 2097152                 (exactly fills 65536 fl)
//   Mtf bf16 frag-major     @ 2162688
//   Wf  bf16 frag-major     @ 2424832
//   gs  [128]               @ 2449408
//   qbf bf16 frag-major     @ 2449536

__device__ __forceinline__ unsigned short f2bf(float f) {  // RNE, finite inputs
  unsigned u = __float_as_uint(f);
  u += 0x7fff + ((u >> 16) & 1);
  return (unsigned short)(u >> 16);
}
__device__ __forceinline__ float bf2f(unsigned short s) {
  return __uint_as_float(((unsigned)s) << 16);
}
// [128 rows][32 px] ushort buffer, 16B-granule XOR swizzle (2-way max per 16-lane phase)
__device__ __forceinline__ int swz(int row, int px) {
  return row * 32 + ((((px >> 3) ^ ((row >> 1) & 3)) << 3) | (px & 7));
}

// ---------------- K0: pack Wf frag-major, gs ----------------
__global__ void k0_init(const float* __restrict__ wqkv, const float* __restrict__ g,
                        float* __restrict__ ws) {
  int tid = blockIdx.x * blockDim.x + threadIdx.x;
  int stride = gridDim.x * blockDim.x;
  unsigned short* Wf = (unsigned short*)(ws + 2424832);
  for (int i = tid; i < 49152; i += stride) {
    int o = i >> 7, c = i & 127;
    int f = (o >> 4) * 4 + (c >> 5);
    int lane = (o & 15) + (((c >> 3) & 3) << 4);
    Wf[f * 512 + lane * 8 + (c & 7)] = f2bf(wqkv[o * 128 + c]);
  }
  float* gs = ws + 2449408;
  if (tid < 128) gs[tid] = g[tid] * 11.313708498984761f;  // sqrt(128)
}

// ---------------- K1: rmsnorm + MFMA qkv + q-softmax + MFMA S/Z partials ----------------
__global__ __launch_bounds__(256, 4) void k1_qkv(
    const float* __restrict__ x, const unsigned short* __restrict__ Wf,
    const float* __restrict__ gs, unsigned short* __restrict__ Sp,
    unsigned short* __restrict__ Zp, unsigned short* __restrict__ qbf) {
  __shared__ __align__(16) unsigned short xnf[16 * 512];   // 16 KB: B-frags of xn
  __shared__ __align__(16) unsigned short kbuf[128 * 32];  // 8 KB: exp(k) half, swizzled
  __shared__ __align__(16) unsigned short vbuf[128 * 32];  // 8 KB: v half, swizzled
  __shared__ float ssred[256];                             // 1 KB
  const int b = blockIdx.x >> 5, grp = blockIdx.x & 31;
  const int tid = threadIdx.x;
  const int p = tid & 63, w = tid >> 6;
  const int chunk = __builtin_amdgcn_readfirstlane(w);   // wave id == head id
  const int l = p, quad = l >> 4, l16 = l & 15;

  short8 ones;                 // bf16 1.0 in every slot (B operand for Z row-sums)
#pragma unroll
  for (int j = 0; j < 8; j++) ones[j] = (short)0x3F80;

  f32x4 accS[2][2] = {};       // S partial: [d-block][e-block], head = chunk
  f32x4 accZ[2] = {};          // Z partial: [d-block] (cols replicated)

  const float* xbase = x + (size_t)b * 524288;
  float xr[32];
  {  // prologue: load tile grp*2's column (c = chunk*32+i) for pixel p
    const float* xb = xbase + grp * 128 + p;
#pragma unroll
    for (int i = 0; i < 32; i++) xr[i] = xb[(size_t)(chunk * 32 + i) * 4096];
  }

#pragma unroll 1
  for (int t = 0; t < 2; t++) {
    const int tile = grp * 2 + t;
    // phase 1: rmsnorm on prefetched xr
    float ss = 0.f;
#pragma unroll
    for (int i = 0; i < 32; i++) ss += xr[i] * xr[i];
    ssred[w * 64 + p] = ss;
    __syncthreads();  // (A)
    float tot = ssred[p] + ssred[64 + p] + ssred[128 + p] + ssred[192 + p];
    float inv = 1.0f / fmaxf(sqrtf(tot), 1e-12f);
#pragma unroll
    for (int q8 = 0; q8 < 4; q8++) {
      short8 v8;
#pragma unroll
      for (int j = 0; j < 8; j++) {
        int i = q8 * 8 + j;
        v8[j] = (short)f2bf(xr[i] * gs[chunk * 32 + i] * inv);
      }
      *(short8*)&xnf[(chunk * 4 + (p >> 4)) * 512 + ((p & 15) + q8 * 16) * 8] = v8;
    }
    __syncthreads();  // (B) xnf ready

    // prefetch next sub-tile's x under the MFMA sections
    if (t == 0) {
      const float* xb = xbase + (tile + 1) * 64 + p;
#pragma unroll
      for (int i = 0; i < 32; i++) xr[i] = xb[(size_t)(chunk * 32 + i) * 4096];
    }

    const short8* Wfv = (const short8*)Wf;
    // ---- q section (rows = head chunk, all 64 px) ----
    {
      f32x4 acc[2][4] = {};
#pragma unroll
      for (int k0 = 0; k0 < 4; k0++) {
        short8 bfr[4];
#pragma unroll
        for (int n0 = 0; n0 < 4; n0++)
          bfr[n0] = *(const short8*)&xnf[(k0 * 4 + n0) * 512 + l * 8];
#pragma unroll
        for (int off = 0; off < 2; off++) {
          short8 afr = Wfv[((chunk * 2 + off) * 4 + k0) * 64 + l];
#pragma unroll
          for (int n0 = 0; n0 < 4; n0++)
            acc[off][n0] = __builtin_amdgcn_mfma_f32_16x16x32_bf16(afr, bfr[n0], acc[off][n0], 0, 0, 0);
        }
      }
#pragma unroll
      for (int n0 = 0; n0 < 4; n0++) {
        float m = -1e30f;
#pragma unroll
        for (int off = 0; off < 2; off++)
#pragma unroll
          for (int r = 0; r < 4; r++) m = fmaxf(m, acc[off][n0][r]);
        m = fmaxf(m, __shfl_xor(m, 16, 64));
        m = fmaxf(m, __shfl_xor(m, 32, 64));
        float e[2][4]; float sum = 0.f;
#pragma unroll
        for (int off = 0; off < 2; off++)
#pragma unroll
          for (int r = 0; r < 4; r++) {
            e[off][r] = __expf(acc[off][n0][r] - m);
            sum += e[off][r];
          }
        sum += __shfl_xor(sum, 16, 64);
        sum += __shfl_xor(sum, 32, 64);
        float rs = 0.17677669529663687f / sum;  // dh^-0.5 / sum
        int qbase = ((b * 64 + tile) * 16 + chunk * 4 + n0) * 512;
#pragma unroll
        for (int off = 0; off < 2; off++) {
          int lane2 = l16 + ((off * 2 + (quad >> 1)) << 4);
          bf16x4 qv;
#pragma unroll
          for (int r = 0; r < 4; r++) qv[r] = (short)f2bf(e[off][r] * rs);
          *(bf16x4*)&qbf[qbase + lane2 * 8 + (quad & 1) * 4] = qv;
        }
      }
    }

    // ---- k/v halves + phase-4 (per 32-px half; wave-private LDS rows) ----
#pragma unroll
    for (int h2 = 0; h2 < 2; h2++) {
      // k-section half: W rows 128 + chunk*32 .. +32, px half h2
      {
        f32x4 acck[2][2] = {};
#pragma unroll
        for (int k0 = 0; k0 < 4; k0++) {
          short8 bf0 = *(const short8*)&xnf[(k0 * 4 + (h2 * 2 + 0)) * 512 + l * 8];
          short8 bf1 = *(const short8*)&xnf[(k0 * 4 + (h2 * 2 + 1)) * 512 + l * 8];
#pragma unroll
          for (int off = 0; off < 2; off++) {
            short8 afr = Wfv[((8 + chunk * 2 + off) * 4 + k0) * 64 + l];
            acck[off][0] = __builtin_amdgcn_mfma_f32_16x16x32_bf16(afr, bf0, acck[off][0], 0, 0, 0);
            acck[off][1] = __builtin_amdgcn_mfma_f32_16x16x32_bf16(afr, bf1, acck[off][1], 0, 0, 0);
          }
        }
#pragma unroll
        for (int off = 0; off < 2; off++)
#pragma unroll
          for (int n0l = 0; n0l < 2; n0l++)
#pragma unroll
            for (int r = 0; r < 4; r++) {
              int row = chunk * 32 + off * 16 + quad * 4 + r;
              kbuf[swz(row, n0l * 16 + l16)] = f2bf(__expf(acck[off][n0l][r]));
            }
      }
      // v-section half: W rows 256 + chunk*32 .. +32, px half h2
      {
        f32x4 accv[2][2] = {};
#pragma unroll
        for (int k0 = 0; k0 < 4; k0++) {
          short8 bf0 = *(const short8*)&xnf[(k0 * 4 + (h2 * 2 + 0)) * 512 + l * 8];
          short8 bf1 = *(const short8*)&xnf[(k0 * 4 + (h2 * 2 + 1)) * 512 + l * 8];
#pragma unroll
          for (int off = 0; off < 2; off++) {
            short8 afr = Wfv[((16 + chunk * 2 + off) * 4 + k0) * 64 + l];
            accv[off][0] = __builtin_amdgcn_mfma_f32_16x16x32_bf16(afr, bf0, accv[off][0], 0, 0, 0);
            accv[off][1] = __builtin_amdgcn_mfma_f32_16x16x32_bf16(afr, bf1, accv[off][1], 0, 0, 0);
          }
        }
#pragma unroll
        for (int off = 0; off < 2; off++)
#pragma unroll
          for (int n0l = 0; n0l < 2; n0l++)
#pragma unroll
            for (int r = 0; r < 4; r++) {
              int row = chunk * 32 + off * 16 + quad * 4 + r;
              vbuf[swz(row, n0l * 16 + l16)] = f2bf(accv[off][n0l][r]);
            }
      }
      // phase-4 half: S += expk . v^T, Z += expk . 1  (same-wave RAW; lgkm auto)
      {
        const int rowA = chunk * 32 + l16;
        short8 ak0 = *(const short8*)&kbuf[swz(rowA, quad * 8)];
        short8 ak1 = *(const short8*)&kbuf[swz(rowA + 16, quad * 8)];
        short8 av0 = *(const short8*)&vbuf[swz(rowA, quad * 8)];
        short8 av1 = *(const short8*)&vbuf[swz(rowA + 16, quad * 8)];
        accS[0][0] = __builtin_amdgcn_mfma_f32_16x16x32_bf16(ak0, av0, accS[0][0], 0, 0, 0);
        accS[0][1] = __builtin_amdgcn_mfma_f32_16x16x32_bf16(ak0, av1, accS[0][1], 0, 0, 0);
        accS[1][0] = __builtin_amdgcn_mfma_f32_16x16x32_bf16(ak1, av0, accS[1][0], 0, 0, 0);
        accS[1][1] = __builtin_amdgcn_mfma_f32_16x16x32_bf16(ak1, av1, accS[1][1], 0, 0, 0);
        accZ[0] = __builtin_amdgcn_mfma_f32_16x16x32_bf16(ak0, ones, accZ[0], 0, 0, 0);
        accZ[1] = __builtin_amdgcn_mfma_f32_16x16x32_bf16(ak1, ones, accZ[1], 0, 0, 0);
      }
    }
  }

  // write bf16 partials frag-major (coalesced 8B stores, no atomics)
  unsigned short* Spb = Sp + (size_t)(b * 32 + grp) * 4096 + chunk * 1024;
#pragma unroll
  for (int mm = 0; mm < 2; mm++)
#pragma unroll
    for (int nn = 0; nn < 2; nn++) {
      bf16x4 sv;
#pragma unroll
      for (int r = 0; r < 4; r++) sv[r] = (short)f2bf(accS[mm][nn][r]);
      *(bf16x4*)&Spb[(mm * 2 + nn) * 256 + l * 4] = sv;
    }
  if (l16 == 0) {
#pragma unroll
    for (int mm = 0; mm < 2; mm++) {
      bf16x4 zv;
#pragma unroll
      for (int r = 0; r < 4; r++) zv[r] = (short)f2bf(accZ[mm][r]);
      *(bf16x4*)&Zp[(b * 32 + grp) * 128 + chunk * 32 + mm * 16 + quad * 4] = zv;
    }
  }
}

// ---------------- K2: reduce partials + context + fold w_out -> Mtf ----------------
__global__ void k2_ctx(const unsigned short* __restrict__ Sp, const unsigned short* __restrict__ Zp,
                       const float* __restrict__ memkv, const float* __restrict__ wout,
                       unsigned short* __restrict__ Mtf) {
  __shared__ float C[1024];      // this quarter's rows [32][32]
  __shared__ float zinv[128];
  __shared__ float wl[128 * 33]; // wout[:, qr*32 .. +32] staged, padded (+1)
  const int b = blockIdx.x >> 2, qr = blockIdx.x & 3, tid = threadIdx.x;
  // stage wout column block (coalesced: 128B runs)
  for (int i = tid; i < 4096; i += 256) {
    int o = i >> 5, e = i & 31;
    wl[o * 33 + e] = wout[o * 128 + qr * 32 + e];
  }
  if (tid < 128) {
    float z = 0.f;
#pragma unroll
    for (int g = 0; g < 32; g++) z += bf2f(Zp[(b * 32 + g) * 128 + tid]);
    float zm = 0.f;
#pragma unroll
    for (int j = 0; j < 4; j++) zm += __expf(memkv[tid * 4 + j]);
    zinv[tid] = 1.0f / (z + zm);
  }
  __syncthreads();
  for (int i = tid; i < 1024; i += 256) {
    int idx = qr * 1024 + i;
    int hd = idx >> 5, e = idx & 31, h = hd >> 5, d = hd & 31;
    // frag-major Sp: lane = (e&15) + ((d>>2)&3)*16, reg = d&3
    int fofs = h * 1024 + ((d >> 4) * 2 + (e >> 4)) * 256 + ((e & 15) + ((d >> 2) & 3) * 16) * 4 + (d & 3);
    float s = 0.f;
#pragma unroll
    for (int g = 0; g < 32; g++) s += bf2f(Sp[(size_t)(b * 32 + g) * 4096 + fofs]);
    float sm = 0.f;
#pragma unroll
    for (int j = 0; j < 4; j++)
      sm += __expf(memkv[hd * 4 + j]) * memkv[512 + (h * 32 + e) * 4 + j];
    C[i] = (s + sm) * zinv[hd];
  }
  __syncthreads();
  for (int i = tid; i < 4096; i += 256) {
    int hd = qr * 32 + (i >> 7);
    int o = i & 127;
    float a = 0.f;
#pragma unroll
    for (int e = 0; e < 32; e++) a += wl[o * 33 + e] * C[(i >> 7) * 32 + e];
    int f = (o >> 4) * 4 + (hd >> 5);
    int lane = (o & 15) + (((hd >> 3) & 3) << 4);
    Mtf[(size_t)b * 16384 + f * 512 + lane * 8 + (hd & 7)] = f2bf(a);
  }
}

// ---------------- K3: out = Mtf x q + b_out (MFMA, LDS-restaged stores) ----------------
__global__ __launch_bounds__(256) void k3_out(
    const unsigned short* __restrict__ qbf, const unsigned short* __restrict__ Mtf,
    const float* __restrict__ bout, float* __restrict__ out) {
  __shared__ __align__(16) unsigned short qf[16 * 512];
  __shared__ __align__(16) float obuf[128 * 68];
  const int b = blockIdx.x >> 6, tile = blockIdx.x & 63;
  const int tid = threadIdx.x;
  const int l = tid & 63, quad = l >> 4, l16 = l & 15;
  const int chunk = __builtin_amdgcn_readfirstlane(tid >> 6);
  const short8* qv = (const short8*)qbf;
  const int base = ((b * 64 + tile) * 16) * 64;  // short8 units
#pragma unroll
  for (int r = 0; r < 4; r++) {
    int cid = tid + 256 * r;
    *(short8*)&qf[cid * 8] = qv[base + cid];
  }
  __syncthreads();
  f32x4 acc[2][4] = {};
  const short8* Mv = (const short8*)Mtf;
#pragma unroll
  for (int k0 = 0; k0 < 4; k0++) {
    short8 bfr[4];
#pragma unroll
    for (int n0 = 0; n0 < 4; n0++)
      bfr[n0] = *(const short8*)&qf[(k0 * 4 + n0) * 512 + l * 8];
#pragma unroll
    for (int mm = 0; mm < 2; mm++) {
      short8 afr = Mv[((size_t)b * 32 + (chunk * 2 + mm) * 4 + k0) * 64 + l];
#pragma unroll
      for (int n0 = 0; n0 < 4; n0++)
        acc[mm][n0] = __builtin_amdgcn_mfma_f32_16x16x32_bf16(afr, bfr[n0], acc[mm][n0], 0, 0, 0);
    }
  }
#pragma unroll
  for (int mm = 0; mm < 2; mm++)
#pragma unroll
    for (int r = 0; r < 4; r++) {
      float bv = bout[chunk * 32 + mm * 16 + quad * 4 + r];
#pragma unroll
      for (int n0 = 0; n0 < 4; n0++) {
        int o = chunk * 32 + mm * 16 + quad * 4 + r;
        obuf[o * 68 + n0 * 16 + l16] = acc[mm][n0][r] + bv;
      }
    }
  __syncthreads();
#pragma unroll
  for (int rr = 0; rr < 8; rr++) {
    int idx = tid + 256 * rr;     // 0..2047 = 128 rows * 16 float4
    int row = idx >> 4, c4 = idx & 15;
    f32x4 v = *(const f32x4*)&obuf[row * 68 + c4 * 4];
    *(f32x4*)&out[((size_t)b * 128 + row) * 4096 + tile * 64 + c4 * 4] = v;
  }
}

extern "C" void kernel_launch(void* const* d_in, const int* in_sizes, int n_in,
                              void* d_out, int out_size, void* d_ws, size_t ws_size,
                              hipStream_t stream) {
  const float* x     = (const float*)d_in[0];
  const float* g     = (const float*)d_in[1];
  const float* wqkv  = (const float*)d_in[2];
  const float* memkv = (const float*)d_in[3];
  const float* wout  = (const float*)d_in[4];
  const float* bout  = (const float*)d_in[5];
  float* out = (float*)d_out;
  float* ws = (float*)d_ws;
  unsigned short* Sp  = (unsigned short*)ws;
  unsigned short* Zp  = (unsigned short*)(ws + 2097152);
  unsigned short* Mtf = (unsigned short*)(ws + 2162688);
  unsigned short* Wf  = (unsigned short*)(ws + 2424832);
  float* gs  = ws + 2449408;
  unsigned short* qbf = (unsigned short*)(ws + 2449536);

  k0_init<<<128, 256, 0, stream>>>(wqkv, g, ws);
  k1_qkv<<<1024, 256, 0, stream>>>(x, Wf, gs, Sp, Zp, qbf);
  k2_ctx<<<128, 256, 0, stream>>>(Sp, Zp, memkv, wout, Mtf);
  k3_out<<<2048, 256, 0, stream>>>(qbf, Mtf, bout, out);
}

// Round 4
// 203.158 us; speedup vs baseline: 1.6612x; 1.6612x over previous
//
#include <hip/hip_runtime.h>
#include <hip/hip_bf16.h>

typedef __attribute__((ext_vector_type(8))) short short8;   // 8 bf16 (A/B frag)
typedef __attribute__((ext_vector_type(4))) short bf16x4;   // 4 bf16 (8B store)
typedef __attribute__((ext_vector_type(4))) float f32x4;    // 4 fp32 (C/D frag)

// b=32, C=128, n=4096, heads=4, dh=32. All I/O fp32; MFMA bf16, fp32 accum.
// K1: grid 1024 = 32 b * 32 groups, 2 tiles of 64 px each; LDS 33 KB (4 blocks/CU
// by LDS). launch_bounds(256,2): (256,4) capped unified VGPR+AGPR at 128 ->
// MFMA accs took AGPRs, only 64 arch VGPRs left -> 650 MB spill traffic (round 3).
// kbuf/vbuf are [128][32] half-width; per tile: q section, then
// 2x { k-half -> v-half -> phase4-half } (same-wave RAW, no barrier).
//
// ws (float units), offsets unchanged:
//   Sp  bf16 frag-major [32][32][4][4x256] @ 0        (exactly fills 2097152 fl)
//   Zp  bf16 [32][32][128]  @ 2097152                 (exactly fills 65536 fl)
//   Mtf bf16 frag-major     @ 2162688
//   Wf  bf16 frag-major     @ 2424832
//   gs  [128]               @ 2449408
//   qbf bf16 frag-major     @ 2449536

__device__ __forceinline__ unsigned short f2bf(float f) {  // RNE, finite inputs
  unsigned u = __float_as_uint(f);
  u += 0x7fff + ((u >> 16) & 1);
  return (unsigned short)(u >> 16);
}
__device__ __forceinline__ float bf2f(unsigned short s) {
  return __uint_as_float(((unsigned)s) << 16);
}
// [128 rows][32 px] ushort buffer, 16B-granule XOR swizzle (2-way max per 16-lane phase)
__device__ __forceinline__ int swz(int row, int px) {
  return row * 32 + ((((px >> 3) ^ ((row >> 1) & 3)) << 3) | (px & 7));
}

// ---------------- K0: pack Wf frag-major, gs ----------------
__global__ void k0_init(const float* __restrict__ wqkv, const float* __restrict__ g,
                        float* __restrict__ ws) {
  int tid = blockIdx.x * blockDim.x + threadIdx.x;
  int stride = gridDim.x * blockDim.x;
  unsigned short* Wf = (unsigned short*)(ws + 2424832);
  for (int i = tid; i < 49152; i += stride) {
    int o = i >> 7, c = i & 127;
    int f = (o >> 4) * 4 + (c >> 5);
    int lane = (o & 15) + (((c >> 3) & 3) << 4);
    Wf[f * 512 + lane * 8 + (c & 7)] = f2bf(wqkv[o * 128 + c]);
  }
  float* gs = ws + 2449408;
  if (tid < 128) gs[tid] = g[tid] * 11.313708498984761f;  // sqrt(128)
}

// ---------------- K1: rmsnorm + MFMA qkv + q-softmax + MFMA S/Z partials ----------------
__global__ __launch_bounds__(256, 2) void k1_qkv(
    const float* __restrict__ x, const unsigned short* __restrict__ Wf,
    const float* __restrict__ gs, unsigned short* __restrict__ Sp,
    unsigned short* __restrict__ Zp, unsigned short* __restrict__ qbf) {
  __shared__ __align__(16) unsigned short xnf[16 * 512];   // 16 KB: B-frags of xn
  __shared__ __align__(16) unsigned short kbuf[128 * 32];  // 8 KB: exp(k) half, swizzled
  __shared__ __align__(16) unsigned short vbuf[128 * 32];  // 8 KB: v half, swizzled
  __shared__ float ssred[256];                             // 1 KB
  const int b = blockIdx.x >> 5, grp = blockIdx.x & 31;
  const int tid = threadIdx.x;
  const int p = tid & 63, w = tid >> 6;
  const int chunk = __builtin_amdgcn_readfirstlane(w);   // wave id == head id
  const int l = p, quad = l >> 4, l16 = l & 15;

  short8 ones;                 // bf16 1.0 in every slot (B operand for Z row-sums)
#pragma unroll
  for (int j = 0; j < 8; j++) ones[j] = (short)0x3F80;

  f32x4 accS[2][2] = {};       // S partial: [d-block][e-block], head = chunk
  f32x4 accZ[2] = {};          // Z partial: [d-block] (cols replicated)

  const float* xbase = x + (size_t)b * 524288;
  float xr[32];
  {  // prologue: load tile grp*2's column (c = chunk*32+i) for pixel p
    const float* xb = xbase + grp * 128 + p;
#pragma unroll
    for (int i = 0; i < 32; i++) xr[i] = xb[(size_t)(chunk * 32 + i) * 4096];
  }

#pragma unroll 1
  for (int t = 0; t < 2; t++) {
    const int tile = grp * 2 + t;
    // phase 1: rmsnorm on prefetched xr
    float ss = 0.f;
#pragma unroll
    for (int i = 0; i < 32; i++) ss += xr[i] * xr[i];
    ssred[w * 64 + p] = ss;
    __syncthreads();  // (A)
    float tot = ssred[p] + ssred[64 + p] + ssred[128 + p] + ssred[192 + p];
    float inv = 1.0f / fmaxf(sqrtf(tot), 1e-12f);
#pragma unroll
    for (int q8 = 0; q8 < 4; q8++) {
      short8 v8;
#pragma unroll
      for (int j = 0; j < 8; j++) {
        int i = q8 * 8 + j;
        v8[j] = (short)f2bf(xr[i] * gs[chunk * 32 + i] * inv);
      }
      *(short8*)&xnf[(chunk * 4 + (p >> 4)) * 512 + ((p & 15) + q8 * 16) * 8] = v8;
    }
    __syncthreads();  // (B) xnf ready

    // prefetch next sub-tile's x under the MFMA sections
    if (t == 0) {
      const float* xb = xbase + (tile + 1) * 64 + p;
#pragma unroll
      for (int i = 0; i < 32; i++) xr[i] = xb[(size_t)(chunk * 32 + i) * 4096];
    }

    const short8* Wfv = (const short8*)Wf;
    // ---- q section (rows = head chunk, all 64 px) ----
    {
      f32x4 acc[2][4] = {};
#pragma unroll
      for (int k0 = 0; k0 < 4; k0++) {
        short8 bfr[4];
#pragma unroll
        for (int n0 = 0; n0 < 4; n0++)
          bfr[n0] = *(const short8*)&xnf[(k0 * 4 + n0) * 512 + l * 8];
#pragma unroll
        for (int off = 0; off < 2; off++) {
          short8 afr = Wfv[((chunk * 2 + off) * 4 + k0) * 64 + l];
#pragma unroll
          for (int n0 = 0; n0 < 4; n0++)
            acc[off][n0] = __builtin_amdgcn_mfma_f32_16x16x32_bf16(afr, bfr[n0], acc[off][n0], 0, 0, 0);
        }
      }
#pragma unroll
      for (int n0 = 0; n0 < 4; n0++) {
        float m = -1e30f;
#pragma unroll
        for (int off = 0; off < 2; off++)
#pragma unroll
          for (int r = 0; r < 4; r++) m = fmaxf(m, acc[off][n0][r]);
        m = fmaxf(m, __shfl_xor(m, 16, 64));
        m = fmaxf(m, __shfl_xor(m, 32, 64));
        float e[2][4]; float sum = 0.f;
#pragma unroll
        for (int off = 0; off < 2; off++)
#pragma unroll
          for (int r = 0; r < 4; r++) {
            e[off][r] = __expf(acc[off][n0][r] - m);
            sum += e[off][r];
          }
        sum += __shfl_xor(sum, 16, 64);
        sum += __shfl_xor(sum, 32, 64);
        float rs = 0.17677669529663687f / sum;  // dh^-0.5 / sum
        int qbase = ((b * 64 + tile) * 16 + chunk * 4 + n0) * 512;
#pragma unroll
        for (int off = 0; off < 2; off++) {
          int lane2 = l16 + ((off * 2 + (quad >> 1)) << 4);
          bf16x4 qv;
#pragma unroll
          for (int r = 0; r < 4; r++) qv[r] = (short)f2bf(e[off][r] * rs);
          *(bf16x4*)&qbf[qbase + lane2 * 8 + (quad & 1) * 4] = qv;
        }
      }
    }

    // ---- k/v halves + phase-4 (per 32-px half; wave-private LDS rows) ----
#pragma unroll
    for (int h2 = 0; h2 < 2; h2++) {
      // k-section half: W rows 128 + chunk*32 .. +32, px half h2
      {
        f32x4 acck[2][2] = {};
#pragma unroll
        for (int k0 = 0; k0 < 4; k0++) {
          short8 bf0 = *(const short8*)&xnf[(k0 * 4 + (h2 * 2 + 0)) * 512 + l * 8];
          short8 bf1 = *(const short8*)&xnf[(k0 * 4 + (h2 * 2 + 1)) * 512 + l * 8];
#pragma unroll
          for (int off = 0; off < 2; off++) {
            short8 afr = Wfv[((8 + chunk * 2 + off) * 4 + k0) * 64 + l];
            acck[off][0] = __builtin_amdgcn_mfma_f32_16x16x32_bf16(afr, bf0, acck[off][0], 0, 0, 0);
            acck[off][1] = __builtin_amdgcn_mfma_f32_16x16x32_bf16(afr, bf1, acck[off][1], 0, 0, 0);
          }
        }
#pragma unroll
        for (int off = 0; off < 2; off++)
#pragma unroll
          for (int n0l = 0; n0l < 2; n0l++)
#pragma unroll
            for (int r = 0; r < 4; r++) {
              int row = chunk * 32 + off * 16 + quad * 4 + r;
              kbuf[swz(row, n0l * 16 + l16)] = f2bf(__expf(acck[off][n0l][r]));
            }
      }
      // v-section half: W rows 256 + chunk*32 .. +32, px half h2
      {
        f32x4 accv[2][2] = {};
#pragma unroll
        for (int k0 = 0; k0 < 4; k0++) {
          short8 bf0 = *(const short8*)&xnf[(k0 * 4 + (h2 * 2 + 0)) * 512 + l * 8];
          short8 bf1 = *(const short8*)&xnf[(k0 * 4 + (h2 * 2 + 1)) * 512 + l * 8];
#pragma unroll
          for (int off = 0; off < 2; off++) {
            short8 afr = Wfv[((16 + chunk * 2 + off) * 4 + k0) * 64 + l];
            accv[off][0] = __builtin_amdgcn_mfma_f32_16x16x32_bf16(afr, bf0, accv[off][0], 0, 0, 0);
            accv[off][1] = __builtin_amdgcn_mfma_f32_16x16x32_bf16(afr, bf1, accv[off][1], 0, 0, 0);
          }
        }
#pragma unroll
        for (int off = 0; off < 2; off++)
#pragma unroll
          for (int n0l = 0; n0l < 2; n0l++)
#pragma unroll
            for (int r = 0; r < 4; r++) {
              int row = chunk * 32 + off * 16 + quad * 4 + r;
              vbuf[swz(row, n0l * 16 + l16)] = f2bf(accv[off][n0l][r]);
            }
      }
      // phase-4 half: S += expk . v^T, Z += expk . 1  (same-wave RAW; lgkm auto)
      {
        const int rowA = chunk * 32 + l16;
        short8 ak0 = *(const short8*)&kbuf[swz(rowA, quad * 8)];
        short8 ak1 = *(const short8*)&kbuf[swz(rowA + 16, quad * 8)];
        short8 av0 = *(const short8*)&vbuf[swz(rowA, quad * 8)];
        short8 av1 = *(const short8*)&vbuf[swz(rowA + 16, quad * 8)];
        accS[0][0] = __builtin_amdgcn_mfma_f32_16x16x32_bf16(ak0, av0, accS[0][0], 0, 0, 0);
        accS[0][1] = __builtin_amdgcn_mfma_f32_16x16x32_bf16(ak0, av1, accS[0][1], 0, 0, 0);
        accS[1][0] = __builtin_amdgcn_mfma_f32_16x16x32_bf16(ak1, av0, accS[1][0], 0, 0, 0);
        accS[1][1] = __builtin_amdgcn_mfma_f32_16x16x32_bf16(ak1, av1, accS[1][1], 0, 0, 0);
        accZ[0] = __builtin_amdgcn_mfma_f32_16x16x32_bf16(ak0, ones, accZ[0], 0, 0, 0);
        accZ[1] = __builtin_amdgcn_mfma_f32_16x16x32_bf16(ak1, ones, accZ[1], 0, 0, 0);
      }
    }
  }

  // write bf16 partials frag-major (coalesced 8B stores, no atomics)
  unsigned short* Spb = Sp + (size_t)(b * 32 + grp) * 4096 + chunk * 1024;
#pragma unroll
  for (int mm = 0; mm < 2; mm++)
#pragma unroll
    for (int nn = 0; nn < 2; nn++) {
      bf16x4 sv;
#pragma unroll
      for (int r = 0; r < 4; r++) sv[r] = (short)f2bf(accS[mm][nn][r]);
      *(bf16x4*)&Spb[(mm * 2 + nn) * 256 + l * 4] = sv;
    }
  if (l16 == 0) {
#pragma unroll
    for (int mm = 0; mm < 2; mm++) {
      bf16x4 zv;
#pragma unroll
      for (int r = 0; r < 4; r++) zv[r] = (short)f2bf(accZ[mm][r]);
      *(bf16x4*)&Zp[(b * 32 + grp) * 128 + chunk * 32 + mm * 16 + quad * 4] = zv;
    }
  }
}

// ---------------- K2: reduce partials + context + fold w_out -> Mtf ----------------
// grid 512 = 32 b * 16 slices; each slice owns 8 context rows (one head).
__global__ __launch_bounds__(256) void k2_ctx(
    const unsigned short* __restrict__ Sp, const unsigned short* __restrict__ Zp,
    const float* __restrict__ memkv, const float* __restrict__ wout,
    unsigned short* __restrict__ Mtf) {
  __shared__ float wl[128 * 33];   // wout[:, h*32 .. +32] staged, padded
  __shared__ float Cs[8 * 32];     // context rows [hdi][e]
  __shared__ float zsh[8];
  __shared__ float zinv_s[8];
  const int b = blockIdx.x >> 4, sl = blockIdx.x & 15, tid = threadIdx.x;
  const int hd0 = sl * 8, h = hd0 >> 5;
  // stage wout column block (coalesced 128B runs)
  for (int i = tid; i < 4096; i += 256) {
    int o = i >> 5, e = i & 31;
    wl[o * 33 + e] = wout[o * 128 + h * 32 + e];
  }
  // Z reduce: tid = hdi*32 + g, shuffle within 32-lane segments
  {
    int hdi = tid >> 5, g = tid & 31;
    float zp = bf2f(Zp[(b * 32 + g) * 128 + hd0 + hdi]);
#pragma unroll
    for (int s2 = 1; s2 < 32; s2 <<= 1) zp += __shfl_xor(zp, s2, 32);
    if (g == 0) zsh[hdi] = zp;
  }
  __syncthreads();
  if (tid < 8) {
    int hd = hd0 + tid;
    float zm = 0.f;
#pragma unroll
    for (int j = 0; j < 4; j++) zm += __expf(memkv[hd * 4 + j]);
    zinv_s[tid] = 1.0f / (zsh[tid] + zm);
  }
  __syncthreads();
  // S reduce: one (hdi, e) cell per thread
  {
    int hdi = tid >> 5, e = tid & 31;
    int hd = hd0 + hdi, d = hd & 31;
    int fofs = h * 1024 + ((d >> 4) * 2 + (e >> 4)) * 256 + ((e & 15) + ((d >> 2) & 3) * 16) * 4 + (d & 3);
    const unsigned short* Spb = Sp + (size_t)b * 131072 + fofs;
    float s = 0.f;
#pragma unroll
    for (int g = 0; g < 32; g++) s += bf2f(Spb[g * 4096]);
    float sm = 0.f;
#pragma unroll
    for (int j = 0; j < 4; j++)
      sm += __expf(memkv[hd * 4 + j]) * memkv[512 + (h * 32 + e) * 4 + j];
    Cs[hdi * 32 + e] = (s + sm) * zinv_s[hdi];
  }
  __syncthreads();
  // fold wout: 4 outputs per thread
  for (int i = tid; i < 1024; i += 256) {
    int o = i & 127, hdi = i >> 7;
    float a = 0.f;
#pragma unroll
    for (int e = 0; e < 32; e++) a += wl[o * 33 + e] * Cs[hdi * 32 + e];
    int hd = hd0 + hdi;
    int f = (o >> 4) * 4 + h;
    int lane = (o & 15) + (((hd >> 3) & 3) << 4);
    Mtf[(size_t)b * 16384 + f * 512 + lane * 8 + (hd & 7)] = f2bf(a);
  }
}

// ---------------- K3: out = Mtf x q + b_out (MFMA, LDS-restaged stores) ----------------
__global__ __launch_bounds__(256) void k3_out(
    const unsigned short* __restrict__ qbf, const unsigned short* __restrict__ Mtf,
    const float* __restrict__ bout, float* __restrict__ out) {
  __shared__ __align__(16) unsigned short qf[16 * 512];
  __shared__ __align__(16) float obuf[128 * 68];
  const int b = blockIdx.x >> 6, tile = blockIdx.x & 63;
  const int tid = threadIdx.x;
  const int l = tid & 63, quad = l >> 4, l16 = l & 15;
  const int chunk = __builtin_amdgcn_readfirstlane(tid >> 6);
  const short8* qv = (const short8*)qbf;
  const int base = ((b * 64 + tile) * 16) * 64;  // short8 units
#pragma unroll
  for (int r = 0; r < 4; r++) {
    int cid = tid + 256 * r;
    *(short8*)&qf[cid * 8] = qv[base + cid];
  }
  __syncthreads();
  f32x4 acc[2][4] = {};
  const short8* Mv = (const short8*)Mtf;
#pragma unroll
  for (int k0 = 0; k0 < 4; k0++) {
    short8 bfr[4];
#pragma unroll
    for (int n0 = 0; n0 < 4; n0++)
      bfr[n0] = *(const short8*)&qf[(k0 * 4 + n0) * 512 + l * 8];
#pragma unroll
    for (int mm = 0; mm < 2; mm++) {
      short8 afr = Mv[((size_t)b * 32 + (chunk * 2 + mm) * 4 + k0) * 64 + l];
#pragma unroll
      for (int n0 = 0; n0 < 4; n0++)
        acc[mm][n0] = __builtin_amdgcn_mfma_f32_16x16x32_bf16(afr, bfr[n0], acc[mm][n0], 0, 0, 0);
    }
  }
#pragma unroll
  for (int mm = 0; mm < 2; mm++)
#pragma unroll
    for (int r = 0; r < 4; r++) {
      float bv = bout[chunk * 32 + mm * 16 + quad * 4 + r];
#pragma unroll
      for (int n0 = 0; n0 < 4; n0++) {
        int o = chunk * 32 + mm * 16 + quad * 4 + r;
        obuf[o * 68 + n0 * 16 + l16] = acc[mm][n0][r] + bv;
      }
    }
  __syncthreads();
#pragma unroll
  for (int rr = 0; rr < 8; rr++) {
    int idx = tid + 256 * rr;     // 0..2047 = 128 rows * 16 float4
    int row = idx >> 4, c4 = idx & 15;
    f32x4 v = *(const f32x4*)&obuf[row * 68 + c4 * 4];
    *(f32x4*)&out[((size_t)b * 128 + row) * 4096 + tile * 64 + c4 * 4] = v;
  }
}

extern "C" void kernel_launch(void* const* d_in, const int* in_sizes, int n_in,
                              void* d_out, int out_size, void* d_ws, size_t ws_size,
                              hipStream_t stream) {
  const float* x     = (const float*)d_in[0];
  const float* g     = (const float*)d_in[1];
  const float* wqkv  = (const float*)d_in[2];
  const float* memkv = (const float*)d_in[3];
  const float* wout  = (const float*)d_in[4];
  const float* bout  = (const float*)d_in[5];
  float* out = (float*)d_out;
  float* ws = (float*)d_ws;
  unsigned short* Sp  = (unsigned short*)ws;
  unsigned short* Zp  = (unsigned short*)(ws + 2097152);
  unsigned short* Mtf = (unsigned short*)(ws + 2162688);
  unsigned short* Wf  = (unsigned short*)(ws + 2424832);
  float* gs  = ws + 2449408;
  unsigned short* qbf = (unsigned short*)(ws + 2449536);

  k0_init<<<128, 256, 0, stream>>>(wqkv, g, ws);
  k1_qkv<<<1024, 256, 0, stream>>>(x, Wf, gs, Sp, Zp, qbf);
  k2_ctx<<<512, 256, 0, stream>>>(Sp, Zp, memkv, wout, Mtf);
  k3_out<<<2048, 256, 0, stream>>>(qbf, Mtf, bout, out);
}